// Round 4
// baseline (2584.948 us; speedup 1.0000x reference)
//
#include <hip/hip_runtime.h>

// TwoStreamNet on MI355X — f32 I/O (inputs + d_out), bf16 MFMA internals.

typedef short short8 __attribute__((ext_vector_type(8)));
typedef float floatx4 __attribute__((ext_vector_type(4)));
typedef unsigned short u16;

#define DIMN 256
#define GBM 128
#define GBN 128
#define GBK 64

static const int kNV = 6144;
static const int kNF = 12288;
static const int SLAB = 768;

__device__ __forceinline__ float bf2f(u16 u) {
  union { unsigned int i; float f; } x; x.i = ((unsigned int)u) << 16; return x.f;
}
__device__ __forceinline__ u16 f2bf(float f) {
  union { float f; unsigned int i; } x; x.f = f;
  unsigned int r = x.i + 0x7fffu + ((x.i >> 16) & 1u);
  return (u16)(r >> 16);
}
__device__ __forceinline__ void gld_lds16(const void* g, void* l) {
  __builtin_amdgcn_global_load_lds((__attribute__((address_space(1))) void*)(g),
                                   (__attribute__((address_space(3))) void*)(l),
                                   16, 0, 0);
}

// ---------------- GEMM: P[z] = Aop(M x K) * Bt(256 x K)^T chunk, f32 partials ------
// Aop row-major [M][K] split at K1 between A0/A1 (concat inputs). Per-operand is32:
// f32 operands are loaded+converted in registers; bf16 operands via global_load_lds.
__global__ __launch_bounds__(256, 2)
void gemm_bf16_k(const void* __restrict__ A0, int A0is32,
                 const void* __restrict__ A1, int A1is32, int K1,
                 int lda0, int lda1,
                 const void* __restrict__ Bt, int Btis32, int ldb,
                 float* __restrict__ P, int M, int kchunk)
{
  __shared__ __align__(16) u16 As[2][GBM * GBK];
  __shared__ __align__(16) u16 Bs[2][GBN * GBK];

  const int m0 = blockIdx.x * GBM;
  const int n0 = blockIdx.y * GBN;
  const int kb = blockIdx.z * kchunk;
  const int nkt = kchunk / GBK;

  const int tid = threadIdx.x;
  const int wid = tid >> 6;
  const int lane = tid & 63;
  const int wr = wid >> 1, wc = wid & 1;
  const int srow = lane >> 3;        // 0..7 rows within 1KB chunk
  const int skk = (lane & 7) << 3;   // 0,8,...,56 k-offset

  floatx4 acc[4][4];
  floatx4 zz = {0.f, 0.f, 0.f, 0.f};
#pragma unroll
  for (int i = 0; i < 4; ++i)
#pragma unroll
    for (int j = 0; j < 4; ++j) acc[i][j] = zz;

  auto stage = [&](int buf, int k0) {
    const void* base; int lda, is32, kl;
    if (k0 < K1) { base = A0; lda = lda0; is32 = A0is32; kl = k0; }
    else         { base = A1; lda = lda1; is32 = A1is32; kl = k0 - K1; }
    if (is32) {
      const float* F = (const float*)base;
#pragma unroll
      for (int j = 0; j < 4; ++j) {
        int c = (wid << 2) + j;
        const float* src = F + (size_t)(m0 + (c << 3) + srow) * lda + kl + skk;
        floatx4 f0 = *(const floatx4*)src;
        floatx4 f1 = *(const floatx4*)(src + 4);
        short8 v;
#pragma unroll
        for (int e = 0; e < 4; ++e) { v[e] = (short)f2bf(f0[e]); v[4 + e] = (short)f2bf(f1[e]); }
        *(short8*)&As[buf][(c << 9) + (lane << 3)] = v;
      }
    } else {
      const u16* U = (const u16*)base;
#pragma unroll
      for (int j = 0; j < 4; ++j) {
        int c = (wid << 2) + j;
        gld_lds16(U + (size_t)(m0 + (c << 3) + srow) * lda + kl + skk,
                  (void*)&As[buf][c << 9]);
      }
    }
    if (Btis32) {
      const float* F = (const float*)Bt;
#pragma unroll
      for (int j = 0; j < 4; ++j) {
        int c = (wid << 2) + j;
        const float* src = F + (size_t)(n0 + (c << 3) + srow) * ldb + k0 + skk;
        floatx4 f0 = *(const floatx4*)src;
        floatx4 f1 = *(const floatx4*)(src + 4);
        short8 v;
#pragma unroll
        for (int e = 0; e < 4; ++e) { v[e] = (short)f2bf(f0[e]); v[4 + e] = (short)f2bf(f1[e]); }
        *(short8*)&Bs[buf][(c << 9) + (lane << 3)] = v;
      }
    } else {
      const u16* U = (const u16*)Bt;
#pragma unroll
      for (int j = 0; j < 4; ++j) {
        int c = (wid << 2) + j;
        gld_lds16(U + (size_t)(n0 + (c << 3) + srow) * ldb + k0 + skk,
                  (void*)&Bs[buf][c << 9]);
      }
    }
  };

  int cur = 0;
  stage(0, kb);
  for (int kt = 0; kt < nkt; ++kt) {
    __syncthreads();  // drains vmcnt+lgkmcnt: staging of `cur` complete
    if (kt + 1 < nkt) stage(cur ^ 1, kb + (kt + 1) * GBK);
#pragma unroll
    for (int ks = 0; ks < 2; ++ks) {
      short8 a[4], b[4];
      const int ko = (ks << 5) + ((lane >> 4) << 3);
#pragma unroll
      for (int mi = 0; mi < 4; ++mi)
        a[mi] = *(const short8*)&As[cur][((wr << 6) + (mi << 4) + (lane & 15)) * GBK + ko];
#pragma unroll
      for (int ni = 0; ni < 4; ++ni)
        b[ni] = *(const short8*)&Bs[cur][((wc << 6) + (ni << 4) + (lane & 15)) * GBK + ko];
#pragma unroll
      for (int mi = 0; mi < 4; ++mi)
#pragma unroll
        for (int ni = 0; ni < 4; ++ni)
          acc[mi][ni] = __builtin_amdgcn_mfma_f32_16x16x32_bf16(a[mi], b[ni], acc[mi][ni], 0, 0, 0);
    }
    cur ^= 1;
  }

  float* Pz = P + (size_t)blockIdx.z * (size_t)M * DIMN;
#pragma unroll
  for (int mi = 0; mi < 4; ++mi) {
#pragma unroll
    for (int ni = 0; ni < 4; ++ni) {
      const int mb = m0 + (wr << 6) + (mi << 4) + ((lane >> 4) << 2);
      const int n = n0 + (wc << 6) + (ni << 4) + (lane & 15);
#pragma unroll
      for (int r = 0; r < 4; ++r)
        Pz[(size_t)(mb + r) * DIMN + n] = acc[mi][ni][r];
    }
  }
}

// ---- finalize: t = sum_s P[s]*scale + bias + add(bf16); [relu]; out=t+resid (f32),
// ---- out16 = bf16(t+resid) — either output optional. ------------------------------
__global__ __launch_bounds__(256)
void finalize_k(const float* __restrict__ P, int S, int Mrows, float scale,
                const float* __restrict__ bias, const u16* __restrict__ addmat,
                int do_relu, const float* __restrict__ resid,
                float* __restrict__ out, u16* __restrict__ out16)
{
  const size_t MN = (size_t)Mrows * DIMN;
  const size_t i4 = (((size_t)blockIdx.x * blockDim.x) + threadIdx.x) * 4;
  if (i4 >= MN) return;
  floatx4 v = {0.f, 0.f, 0.f, 0.f};
  for (int s = 0; s < S; ++s) v += *(const floatx4*)(P + (size_t)s * MN + i4);
  const int n = (int)(i4 & 255);
  floatx4 bf = {0.f,0.f,0.f,0.f}, af = {0.f,0.f,0.f,0.f}, rf = {0.f,0.f,0.f,0.f};
  if (bias) bf = *(const floatx4*)(bias + n);
  if (addmat) {
#pragma unroll
    for (int j = 0; j < 4; ++j) af[j] = bf2f(addmat[i4 + j]);
  }
  if (resid) rf = *(const floatx4*)(resid + i4);
  floatx4 o;
#pragma unroll
  for (int j = 0; j < 4; ++j) {
    float t = v[j] * scale + bf[j] + af[j];
    if (do_relu) t = fmaxf(t, 0.f);
    o[j] = t + rf[j];
  }
  if (out) *(floatx4*)(out + i4) = o;
  if (out16) {
    unsigned long long q = 0;
#pragma unroll
    for (int j = 0; j < 4; ++j) q |= ((unsigned long long)f2bf(o[j])) << (16 * j);
    *(unsigned long long*)(out16 + i4) = q;
  }
}

// -------- transpose (f32 or bf16 in, bf16 out): out[c][r] = in[r][c], 64x64 tiles --
__global__ __launch_bounds__(256)
void transpose_k(const void* __restrict__ in, int is32, int ldin,
                 u16* __restrict__ out, int ldout)
{
  __shared__ __align__(16) u16 t[64][64];
  const int c0 = blockIdx.x << 6;
  const int r0 = blockIdx.y << 6;
  const int tid = threadIdx.x;
  const int lr = tid >> 3;          // 0..31
  const int lc = (tid & 7) << 3;    // 0,8,...,56
#pragma unroll
  for (int h = 0; h < 2; ++h) {
    const int r = lr + (h << 5);
    short8 v;
    if (is32) {
      const float* F = (const float*)in;
      const float* src = F + (size_t)(r0 + r) * ldin + (c0 + lc);
      floatx4 f0 = *(const floatx4*)src;
      floatx4 f1 = *(const floatx4*)(src + 4);
#pragma unroll
      for (int e = 0; e < 4; ++e) { v[e] = (short)f2bf(f0[e]); v[4 + e] = (short)f2bf(f1[e]); }
    } else {
      v = *(const short8*)((const u16*)in + (size_t)(r0 + r) * ldin + (c0 + lc));
    }
    *(short8*)&t[r][lc ^ ((r >> 3) << 3)] = v;
  }
  __syncthreads();
#pragma unroll
  for (int h = 0; h < 2; ++h) {
    const int oc = lr + (h << 5);
    short8 v;
#pragma unroll
    for (int e = 0; e < 8; ++e)
      v[e] = (short)t[lc + e][oc ^ ((lc >> 3) << 3)];
    *(short8*)&out[(size_t)(c0 + oc) * ldout + (r0 + lc)] = v;
  }
}

// -------- f = mean_t |x_p[faces[f,t]] - x_d[f]|  (f32 in, bf16 out) ----------------
__global__ __launch_bounds__(256)
void face_gather_k(const float* __restrict__ xp, const float* __restrict__ xd,
                   const int* __restrict__ faces, u16* __restrict__ f)
{
  const int fi = blockIdx.x;
  const int j = threadIdx.x;
  const int a = faces[fi * 3 + 0];
  const int b = faces[fi * 3 + 1];
  const int c = faces[fi * 3 + 2];
  const float xv = xd[(size_t)fi * DIMN + j];
  const float s = fabsf(xp[(size_t)a * DIMN + j] - xv)
                + fabsf(xp[(size_t)b * DIMN + j] - xv)
                + fabsf(xp[(size_t)c * DIMN + j] - xv);
  f[(size_t)fi * DIMN + j] = f2bf(s * (1.0f / 3.0f));
}

extern "C" void kernel_launch(void* const* d_in, const int* in_sizes, int n_in,
                              void* d_out, int out_size, void* d_ws, size_t ws_size,
                              hipStream_t stream)
{
  (void)in_sizes; (void)n_in; (void)out_size; (void)ws_size;
  const float* primal   = (const float*)d_in[0];
  const float* A_primal = (const float*)d_in[1];
  const float* A_dual   = (const float*)d_in[2];
  const float* A        = (const float*)d_in[3];
  const int* faces      = (const int*)d_in[4];
  const float* pW  = (const float*)d_in[5];
  const float* pb  = (const float*)d_in[6];
  const float* pgW = (const float*)d_in[7];
  const float* pgb = (const float*)d_in[8];
  const float* dW  = (const float*)d_in[9];
  const float* db  = (const float*)d_in[10];
  const float* dgW = (const float*)d_in[11];
  const float* dgb = (const float*)d_in[12];
  const float* Wp  = (const float*)d_in[13];
  const float* bp  = (const float*)d_in[14];
  const float* Wd  = (const float*)d_in[15];
  const float* bd  = (const float*)d_in[16];

  char* wsp = (char*)d_ws;
  auto alloc = [&](size_t bytes) -> void* {
    void* p = (void*)wsp;
    wsp += (bytes + 255) & ~(size_t)255;
    return p;
  };
  const size_t NVD = (size_t)kNV * DIMN, NFD = (size_t)kNF * DIMN;
  // ws: 6.3 + 9.4 + 6.3 + 6.3 + 25.2 = ~53.5 MB (<= 73 MB proven-safe)
  u16* XT    = (u16*)alloc(NFD * 2);                 // x^T [256][M] bf16
  u16* slabT = (u16*)alloc((size_t)SLAB * kNV * 2);  // A^T slab / fc^T / f^T (bf16)
  u16* t1    = (u16*)alloc(NFD * 2);                 // Adj@X / Adj@fc / f (bf16)
  u16* fc    = (u16*)alloc(NFD * 2);                 // out_fc / mapped (bf16)
  float* P   = (float*)alloc((size_t)2 * NFD * 4);   // split-K partials 25.2MB

  float* out0  = (float*)d_out;      // out_primal + x_p
  float* out1  = out0 + NVD;         // out_dual + x_d
  float* pouts = out1 + NFD;         // primal_outs x3 (f32)
  float* douts = pouts + 3 * NVD;    // dual_outs x3 (f32)

  auto gemm = [&](const void* A0p, int a0is32, int lda0,
                  const void* A1p, int a1is32, int lda1, int K1,
                  const void* Btp, int btis32, int ldb, int M, int K, int S) {
    gemm_bf16_k<<<dim3(M / GBM, 2, S), dim3(256), 0, stream>>>(
        A0p, a0is32, A1p, a1is32, K1, lda0, lda1, Btp, btis32, ldb, P, M, K / S);
  };
  auto fin = [&](int M, int S, float scale, const float* bias, const u16* add,
                 int relu, const float* resid, float* out, u16* out16) {
    finalize_k<<<dim3((unsigned)((size_t)M * DIMN / 1024)), dim3(256), 0, stream>>>(
        P, S, M, scale, bias, add, relu, resid, out, out16);
  };
  auto tranp = [&](const void* in, int is32, int ldin, u16* out, int ldout,
                   int R, int C) {
    transpose_k<<<dim3(C / 64, R / 64), dim3(256), 0, stream>>>(
        in, is32, ldin, out, ldout);
  };

  // ---- prep: XT = primal^T [256][NV] (bf16); pouts[0] = primal (f32 copy) ----
  tranp(primal, 1, DIMN, XT, kNV, kNV, DIMN);
  hipMemcpyAsync(pouts, primal, NVD * 4, hipMemcpyDeviceToDevice, stream);

  // ---- x_d = (1/3) A^T @ primal, 16 M-slabs of 768 (A column-slab transposed) ----
  for (int s = 0; s < kNF / SLAB; ++s) {
    const int m0 = s * SLAB;
    tranp(A + m0, 1, kNF, slabT, kNV, kNV, SLAB);       // slabT [768][6144] = A^T slab
    gemm(slabT, 0, kNV, nullptr, 0, 0, kNV, XT, 0, kNV, SLAB, kNV, 16);
    fin(SLAB, 16, 1.0f / 3.0f, nullptr, nullptr, 0, nullptr,
        douts + (size_t)m0 * DIMN, nullptr);
  }

  // ---- primal AGG layers (x_p f32 in pouts slots / out0) ----
  const float* xpc = primal;
  for (int i = 0; i < 3; ++i) {
    gemm(A_primal, 1, kNV, nullptr, 0, 0, kNV, XT, 0, kNV, kNV, kNV, 4);   // Ap@X
    fin(kNV, 4, 1.f, nullptr, nullptr, 0, nullptr, nullptr, t1);           // t1 bf16
    gemm(t1, 0, 256, nullptr, 0, 0, 256, pW + (size_t)i * 65536, 1, 256, kNV, 256, 4);
    fin(kNV, 4, 1.f, pb + i * 256, nullptr, 0, nullptr, nullptr, fc);      // fc bf16
    tranp(fc, 0, DIMN, slabT, kNV, kNV, DIMN);                             // fc^T
    gemm(A_primal, 1, kNV, nullptr, 0, 0, kNV, slabT, 0, kNV, kNV, kNV, 4);// Ap@fc
    fin(kNV, 4, 1.f, nullptr, nullptr, 0, nullptr, nullptr, t1);
    gemm(t1, 0, 256, nullptr, 0, 0, 256, pgW + (size_t)i * 65536, 1, 256, kNV, 256, 4);
    float* nxt = (i < 2) ? (pouts + (size_t)(i + 1) * NVD) : out0;
    fin(kNV, 4, 1.f, pgb + i * 256, fc, 1, xpc, nxt, nullptr);             // relu(fc+og)+x
    xpc = nxt;
    if (i < 2) tranp(xpc, 1, DIMN, XT, kNV, kNV, DIMN);
  }

  // ---- dual AGG layers (x_d f32 in douts slots / out1) ----
  const float* xdc = douts;
  tranp(xdc, 1, DIMN, XT, kNF, kNF, DIMN);
  for (int i = 0; i < 3; ++i) {
    gemm(A_dual, 1, kNF, nullptr, 0, 0, kNF, XT, 0, kNF, kNF, kNF, 2);
    fin(kNF, 2, 1.f, nullptr, nullptr, 0, nullptr, nullptr, t1);
    gemm(t1, 0, 256, nullptr, 0, 0, 256, dW + (size_t)i * 65536, 1, 256, kNF, 256, 2);
    fin(kNF, 2, 1.f, db + i * 256, nullptr, 0, nullptr, nullptr, fc);
    tranp(fc, 0, DIMN, slabT, kNF, kNF, DIMN);
    gemm(A_dual, 1, kNF, nullptr, 0, 0, kNF, slabT, 0, kNF, kNF, kNF, 2);
    fin(kNF, 2, 1.f, nullptr, nullptr, 0, nullptr, nullptr, t1);
    gemm(t1, 0, 256, nullptr, 0, 0, 256, dgW + (size_t)i * 65536, 1, 256, kNF, 256, 2);
    float* nxt = (i < 2) ? (douts + (size_t)(i + 1) * NFD) : out1;
    fin(kNF, 2, 1.f, dgb + i * 256, fc, 1, xdc, nxt, nullptr);
    xdc = nxt;
    if (i < 2) tranp(xdc, 1, DIMN, XT, kNF, kNF, DIMN);
  }

  // ---- PDF ----
  face_gather_k<<<dim3(kNF), dim3(256), 0, stream>>>(xpc, xdc, faces, t1);  // f bf16
  tranp(t1, 0, DIMN, slabT, kNF, kNF, DIMN);                                // f^T
  // out_dual = relu([x_d, f] @ Wd^T + bd) + x_d   (in-place on out1)
  gemm(xdc, 1, 256, t1, 0, 256, 256, Wd, 1, 512, kNF, 512, 2);
  fin(kNF, 2, 1.f, bd, nullptr, 1, xdc, out1, nullptr);
  // mapped = A @ f  -> bf16 in fc
  gemm(A, 1, kNF, nullptr, 0, 0, kNF, slabT, 0, kNF, kNV, kNF, 4);
  fin(kNV, 4, 1.f, nullptr, nullptr, 0, nullptr, nullptr, fc);
  // out_primal = relu([x_p, mapped] @ Wp^T + bp) + x_p   (in-place on out0)
  gemm(xpc, 1, 256, fc, 0, 256, 256, Wp, 1, 512, kNV, 512, 4);
  fin(kNV, 4, 1.f, bp, nullptr, 1, xpc, out0, nullptr);
}

// Round 5
// 2162.004 us; speedup vs baseline: 1.1956x; 1.1956x over previous
//
#include <hip/hip_runtime.h>

// TwoStreamNet on MI355X — f32 I/O, bf16 MFMA internals.
// R5: pre-convert adjacencies/weights to bf16 in ws (ws_size ~2.25GB per profile),
//     GBN=256 single-N-tile GEMM (8 waves, 96KB LDS) -> A_dual streamed once/GEMM.

typedef short short8 __attribute__((ext_vector_type(8)));
typedef float floatx4 __attribute__((ext_vector_type(4)));
typedef unsigned short u16;

#define DIMN 256
#define GBM 128
#define GBN 256
#define GBK 64

static const int kNV = 6144;
static const int kNF = 12288;
static const int SLAB = 768;

__device__ __forceinline__ float bf2f(u16 u) {
  union { unsigned int i; float f; } x; x.i = ((unsigned int)u) << 16; return x.f;
}
__device__ __forceinline__ u16 f2bf(float f) {
  union { float f; unsigned int i; } x; x.f = f;
  unsigned int r = x.i + 0x7fffu + ((x.i >> 16) & 1u);
  return (u16)(r >> 16);
}
__device__ __forceinline__ void gld_lds16(const void* g, void* l) {
  __builtin_amdgcn_global_load_lds((__attribute__((address_space(1))) void*)(g),
                                   (__attribute__((address_space(3))) void*)(l),
                                   16, 0, 0);
}

// ---------------- GEMM: P[z] = Aop(M x K) * Bt(256 x K)^T chunk, f32 partials ------
// 512 threads = 8 waves, wave grid 2(M)x4(N), per-wave 64x64 out (4x4 16x16 frags).
// Aop row-major [M][K] split at K1 between A0/A1 (concat inputs). Per-operand is32:
// f32 operands loaded+converted in registers; bf16 operands via global_load_lds.
__global__ __launch_bounds__(512, 1)
void gemm_bf16_k(const void* __restrict__ A0, int A0is32,
                 const void* __restrict__ A1, int A1is32, int K1,
                 int lda0, int lda1,
                 const void* __restrict__ Bt, int Btis32, int ldb,
                 float* __restrict__ P, int M, int kchunk)
{
  __shared__ __align__(16) u16 As[2][GBM * GBK];   // 2 x 16 KB
  __shared__ __align__(16) u16 Bs[2][GBN * GBK];   // 2 x 32 KB

  const int m0 = blockIdx.x * GBM;
  const int kb = blockIdx.z * kchunk;
  const int nkt = kchunk / GBK;

  const int tid = threadIdx.x;
  const int wid = tid >> 6;        // 0..7
  const int lane = tid & 63;
  const int wr = wid >> 2;         // 0..1 (64-row band)
  const int wc = wid & 3;          // 0..3 (64-col band)
  const int srow = lane >> 3;      // 0..7 rows within 1KB chunk
  const int skk = (lane & 7) << 3; // 0,8,...,56 k-offset

  floatx4 acc[4][4];
  floatx4 zz = {0.f, 0.f, 0.f, 0.f};
#pragma unroll
  for (int i = 0; i < 4; ++i)
#pragma unroll
    for (int j = 0; j < 4; ++j) acc[i][j] = zz;

  auto stage = [&](int buf, int k0) {
    const void* base; int lda, is32, kl;
    if (k0 < K1) { base = A0; lda = lda0; is32 = A0is32; kl = k0; }
    else         { base = A1; lda = lda1; is32 = A1is32; kl = k0 - K1; }
    if (is32) {
      const float* F = (const float*)base;
#pragma unroll
      for (int j = 0; j < 2; ++j) {        // A tile: 16 chunks, 2 per wave
        int c = (wid << 1) + j;
        const float* src = F + (size_t)(m0 + (c << 3) + srow) * lda + kl + skk;
        floatx4 f0 = *(const floatx4*)src;
        floatx4 f1 = *(const floatx4*)(src + 4);
        short8 v;
#pragma unroll
        for (int e = 0; e < 4; ++e) { v[e] = (short)f2bf(f0[e]); v[4 + e] = (short)f2bf(f1[e]); }
        *(short8*)&As[buf][(c << 9) + (lane << 3)] = v;
      }
    } else {
      const u16* U = (const u16*)base;
#pragma unroll
      for (int j = 0; j < 2; ++j) {
        int c = (wid << 1) + j;
        gld_lds16(U + (size_t)(m0 + (c << 3) + srow) * lda + kl + skk,
                  (void*)&As[buf][c << 9]);
      }
    }
    if (Btis32) {
      const float* F = (const float*)Bt;
#pragma unroll
      for (int j = 0; j < 4; ++j) {        // B tile: 32 chunks, 4 per wave
        int c = (wid << 2) + j;
        const float* src = F + (size_t)((c << 3) + srow) * ldb + k0 + skk;
        floatx4 f0 = *(const floatx4*)src;
        floatx4 f1 = *(const floatx4*)(src + 4);
        short8 v;
#pragma unroll
        for (int e = 0; e < 4; ++e) { v[e] = (short)f2bf(f0[e]); v[4 + e] = (short)f2bf(f1[e]); }
        *(short8*)&Bs[buf][(c << 9) + (lane << 3)] = v;
      }
    } else {
      const u16* U = (const u16*)Bt;
#pragma unroll
      for (int j = 0; j < 4; ++j) {
        int c = (wid << 2) + j;
        gld_lds16(U + (size_t)((c << 3) + srow) * ldb + k0 + skk,
                  (void*)&Bs[buf][c << 9]);
      }
    }
  };

  int cur = 0;
  stage(0, kb);
  for (int kt = 0; kt < nkt; ++kt) {
    __syncthreads();  // drains vmcnt+lgkmcnt: staging of `cur` complete
    if (kt + 1 < nkt) stage(cur ^ 1, kb + (kt + 1) * GBK);
#pragma unroll
    for (int ks = 0; ks < 2; ++ks) {
      short8 a[4], b[4];
      const int ko = (ks << 5) + ((lane >> 4) << 3);
#pragma unroll
      for (int mi = 0; mi < 4; ++mi)
        a[mi] = *(const short8*)&As[cur][((wr << 6) + (mi << 4) + (lane & 15)) * GBK + ko];
#pragma unroll
      for (int ni = 0; ni < 4; ++ni)
        b[ni] = *(const short8*)&Bs[cur][((wc << 6) + (ni << 4) + (lane & 15)) * GBK + ko];
#pragma unroll
      for (int mi = 0; mi < 4; ++mi)
#pragma unroll
        for (int ni = 0; ni < 4; ++ni)
          acc[mi][ni] = __builtin_amdgcn_mfma_f32_16x16x32_bf16(a[mi], b[ni], acc[mi][ni], 0, 0, 0);
    }
    cur ^= 1;
  }

  float* Pz = P + (size_t)blockIdx.z * (size_t)M * DIMN;
#pragma unroll
  for (int mi = 0; mi < 4; ++mi) {
#pragma unroll
    for (int ni = 0; ni < 4; ++ni) {
      const int mb = m0 + (wr << 6) + (mi << 4) + ((lane >> 4) << 2);
      const int n = (wc << 6) + (ni << 4) + (lane & 15);
#pragma unroll
      for (int r = 0; r < 4; ++r)
        Pz[(size_t)(mb + r) * DIMN + n] = acc[mi][ni][r];
    }
  }
}

// ---- finalize: t = sum_s P[s]*scale + bias + add(bf16); [relu]; +resid ->
// ---- out (f32) and/or out16 (bf16). -----------------------------------------------
__global__ __launch_bounds__(256)
void finalize_k(const float* __restrict__ P, int S, int Mrows, float scale,
                const float* __restrict__ bias, const u16* __restrict__ addmat,
                int do_relu, const float* __restrict__ resid,
                float* __restrict__ out, u16* __restrict__ out16)
{
  const size_t MN = (size_t)Mrows * DIMN;
  const size_t i4 = (((size_t)blockIdx.x * blockDim.x) + threadIdx.x) * 4;
  if (i4 >= MN) return;
  floatx4 v = {0.f, 0.f, 0.f, 0.f};
  for (int s = 0; s < S; ++s) v += *(const floatx4*)(P + (size_t)s * MN + i4);
  const int n = (int)(i4 & 255);
  floatx4 bf = {0.f,0.f,0.f,0.f}, af = {0.f,0.f,0.f,0.f}, rf = {0.f,0.f,0.f,0.f};
  if (bias) bf = *(const floatx4*)(bias + n);
  if (addmat) {
#pragma unroll
    for (int j = 0; j < 4; ++j) af[j] = bf2f(addmat[i4 + j]);
  }
  if (resid) rf = *(const floatx4*)(resid + i4);
  floatx4 o;
#pragma unroll
  for (int j = 0; j < 4; ++j) {
    float t = v[j] * scale + bf[j] + af[j];
    if (do_relu) t = fmaxf(t, 0.f);
    o[j] = t + rf[j];
  }
  if (out) *(floatx4*)(out + i4) = o;
  if (out16) {
    unsigned long long q = 0;
#pragma unroll
    for (int j = 0; j < 4; ++j) q |= ((unsigned long long)f2bf(o[j])) << (16 * j);
    *(unsigned long long*)(out16 + i4) = q;
  }
}

// -------- transpose (f32 or bf16 in, bf16 out): out[c][r] = in[r][c], 64x64 tiles --
__global__ __launch_bounds__(256)
void transpose_k(const void* __restrict__ in, int is32, int ldin,
                 u16* __restrict__ out, int ldout)
{
  __shared__ __align__(16) u16 t[64][64];
  const int c0 = blockIdx.x << 6;
  const int r0 = blockIdx.y << 6;
  const int tid = threadIdx.x;
  const int lr = tid >> 3;          // 0..31
  const int lc = (tid & 7) << 3;    // 0,8,...,56
#pragma unroll
  for (int h = 0; h < 2; ++h) {
    const int r = lr + (h << 5);
    short8 v;
    if (is32) {
      const float* F = (const float*)in;
      const float* src = F + (size_t)(r0 + r) * ldin + (c0 + lc);
      floatx4 f0 = *(const floatx4*)src;
      floatx4 f1 = *(const floatx4*)(src + 4);
#pragma unroll
      for (int e = 0; e < 4; ++e) { v[e] = (short)f2bf(f0[e]); v[4 + e] = (short)f2bf(f1[e]); }
    } else {
      v = *(const short8*)((const u16*)in + (size_t)(r0 + r) * ldin + (c0 + lc));
    }
    *(short8*)&t[r][lc ^ ((r >> 3) << 3)] = v;
  }
  __syncthreads();
#pragma unroll
  for (int h = 0; h < 2; ++h) {
    const int oc = lr + (h << 5);
    short8 v;
#pragma unroll
    for (int e = 0; e < 8; ++e)
      v[e] = (short)t[lc + e][oc ^ ((lc >> 3) << 3)];
    *(short8*)&out[(size_t)(c0 + oc) * ldout + (r0 + lc)] = v;
  }
}

// -------- elementwise f32 -> bf16 convert (8 elems/thread) --------------------------
__global__ __launch_bounds__(256)
void cvt8_k(const float* __restrict__ in, u16* __restrict__ out, size_t n)
{
  const size_t i = (((size_t)blockIdx.x << 8) + threadIdx.x) << 3;
  if (i >= n) return;
  floatx4 f0 = *(const floatx4*)(in + i);
  floatx4 f1 = *(const floatx4*)(in + i + 4);
  short8 v;
#pragma unroll
  for (int e = 0; e < 4; ++e) { v[e] = (short)f2bf(f0[e]); v[4 + e] = (short)f2bf(f1[e]); }
  *(short8*)(out + i) = v;
}

// -------- f = mean_t |x_p[faces[f,t]] - x_d[f]|  (f32 in, bf16 out) ----------------
__global__ __launch_bounds__(256)
void face_gather_k(const float* __restrict__ xp, const float* __restrict__ xd,
                   const int* __restrict__ faces, u16* __restrict__ f)
{
  const int fi = blockIdx.x;
  const int j = threadIdx.x;
  const int a = faces[fi * 3 + 0];
  const int b = faces[fi * 3 + 1];
  const int c = faces[fi * 3 + 2];
  const float xv = xd[(size_t)fi * DIMN + j];
  const float s = fabsf(xp[(size_t)a * DIMN + j] - xv)
                + fabsf(xp[(size_t)b * DIMN + j] - xv)
                + fabsf(xp[(size_t)c * DIMN + j] - xv);
  f[(size_t)fi * DIMN + j] = f2bf(s * (1.0f / 3.0f));
}

extern "C" void kernel_launch(void* const* d_in, const int* in_sizes, int n_in,
                              void* d_out, int out_size, void* d_ws, size_t ws_size,
                              hipStream_t stream)
{
  (void)in_sizes; (void)n_in; (void)out_size;
  const float* primal   = (const float*)d_in[0];
  const float* A_primal = (const float*)d_in[1];
  const float* A_dual   = (const float*)d_in[2];
  const float* A        = (const float*)d_in[3];
  const int* faces      = (const int*)d_in[4];
  const float* pW  = (const float*)d_in[5];
  const float* pb  = (const float*)d_in[6];
  const float* pgW = (const float*)d_in[7];
  const float* pgb = (const float*)d_in[8];
  const float* dW  = (const float*)d_in[9];
  const float* db  = (const float*)d_in[10];
  const float* dgW = (const float*)d_in[11];
  const float* dgb = (const float*)d_in[12];
  const float* Wp  = (const float*)d_in[13];
  const float* bp  = (const float*)d_in[14];
  const float* Wd  = (const float*)d_in[15];
  const float* bd  = (const float*)d_in[16];

  char* wsp = (char*)d_ws;
  auto alloc = [&](size_t bytes) -> void* {
    void* p = (void*)wsp;
    wsp += (bytes + 255) & ~(size_t)255;
    return p;
  };
  const size_t NVD = (size_t)kNV * DIMN, NFD = (size_t)kNF * DIMN;
  // small buffers (~130 MB)
  u16* XT    = (u16*)alloc(NFD * 2);                 // x^T [256][M] bf16
  u16* TB    = (u16*)alloc((size_t)SLAB * kNV * 2);  // fc^T / f^T / A^T slab (bf16)
  u16* t1    = (u16*)alloc(NFD * 2);                 // Adj@X / Adj@fc / f (bf16)
  u16* fc    = (u16*)alloc(NFD * 2);                 // out_fc / mapped (bf16)
  float* P   = (float*)alloc((size_t)8 * NFD * 4);   // split-K partials 100.7MB
  // big bf16 operand cache (~682 MB) — used only if ws_size allows
  const size_t bigElems = (size_t)kNF * kNF + (size_t)kNF * kNV +
                          (size_t)kNV * kNF + (size_t)kNV * kNV + 1048576;
  const size_t need = (size_t)(wsp - (char*)d_ws) + bigElems * 2 + 4096;
  const bool big = ws_size >= need;
  u16 *Ad16 = nullptr, *At16 = nullptr, *A16 = nullptr, *Ap16 = nullptr, *W16 = nullptr;
  if (big) {
    Ad16 = (u16*)alloc((size_t)kNF * kNF * 2);
    At16 = (u16*)alloc((size_t)kNF * kNV * 2);
    A16  = (u16*)alloc((size_t)kNV * kNF * 2);
    Ap16 = (u16*)alloc((size_t)kNV * kNV * 2);
    W16  = (u16*)alloc((size_t)1048576 * 2);
  }

  float* out0  = (float*)d_out;      // out_primal + x_p
  float* out1  = out0 + NVD;         // out_dual + x_d
  float* pouts = out1 + NFD;         // primal_outs x3 (f32)
  float* douts = pouts + 3 * NVD;    // dual_outs x3 (f32)

  auto gemm = [&](const void* A0p, int a0is32, int lda0,
                  const void* A1p, int a1is32, int lda1, int K1,
                  const void* Btp, int btis32, int ldb, int M, int K, int S) {
    gemm_bf16_k<<<dim3(M / GBM, 1, S), dim3(512), 0, stream>>>(
        A0p, a0is32, A1p, a1is32, K1, lda0, lda1, Btp, btis32, ldb, P, M, K / S);
  };
  auto fin = [&](int M, int S, float scale, const float* bias, const u16* add,
                 int relu, const float* resid, float* out, u16* out16) {
    finalize_k<<<dim3((unsigned)((size_t)M * DIMN / 1024)), dim3(256), 0, stream>>>(
        P, S, M, scale, bias, add, relu, resid, out, out16);
  };
  auto tranp = [&](const void* in, int is32, int ldin, u16* out, int ldout,
                   int R, int C) {
    transpose_k<<<dim3(C / 64, R / 64), dim3(256), 0, stream>>>(
        in, is32, ldin, out, ldout);
  };
  auto cvt = [&](const float* in, u16* out, size_t n) {
    cvt8_k<<<dim3((unsigned)(n / 2048)), dim3(256), 0, stream>>>(in, out, n);
  };

  // ---- operand views: bf16 cache when big, else raw f32 via is32 path ----
  const void *AdP, *ApP, *AP, *pWP, *pgWP, *dWP, *dgWP, *WpP, *WdP;
  int cf;  // is32 flag for converted operands
  if (big) {
    cvt(A_dual, Ad16, (size_t)kNF * kNF);
    cvt(A_primal, Ap16, (size_t)kNV * kNV);
    cvt(A, A16, (size_t)kNV * kNF);
    tranp(A, 1, kNF, At16, kNV, kNV, kNF);             // At16 [12288][6144]
    cvt(pW,  W16 + 0,      196608);
    cvt(pgW, W16 + 196608, 196608);
    cvt(dW,  W16 + 393216, 196608);
    cvt(dgW, W16 + 589824, 196608);
    cvt(Wp,  W16 + 786432, 131072);
    cvt(Wd,  W16 + 917504, 131072);
    AdP = Ad16; ApP = Ap16; AP = A16; cf = 0;
    pWP = W16; pgWP = W16 + 196608; dWP = W16 + 393216; dgWP = W16 + 589824;
    WpP = W16 + 786432; WdP = W16 + 917504;
  } else {
    AdP = A_dual; ApP = A_primal; AP = A; cf = 1;
    pWP = pW; pgWP = pgW; dWP = dW; dgWP = dgW; WpP = Wp; WdP = Wd;
  }
  const size_t W3 = 65536;  // per-layer weight stride (elems)

  // ---- prep: XT = primal^T [256][NV] (bf16); pouts[0] = primal (f32 copy) ----
  tranp(primal, 1, DIMN, XT, kNV, kNV, DIMN);
  hipMemcpyAsync(pouts, primal, NVD * 4, hipMemcpyDeviceToDevice, stream);

  // ---- x_d = (1/3) A^T @ primal ----
  if (big) {
    gemm(At16, 0, kNV, nullptr, 0, 0, kNV, XT, 0, kNV, kNF, kNV, 8);
    fin(kNF, 8, 1.0f / 3.0f, nullptr, nullptr, 0, nullptr, douts, nullptr);
  } else {
    for (int s = 0; s < kNF / SLAB; ++s) {
      const int m0 = s * SLAB;
      tranp(A + m0, 1, kNF, TB, kNV, kNV, SLAB);       // A^T slab [768][6144]
      gemm(TB, 0, kNV, nullptr, 0, 0, kNV, XT, 0, kNV, SLAB, kNV, 16);
      fin(SLAB, 16, 1.0f / 3.0f, nullptr, nullptr, 0, nullptr,
          douts + (size_t)m0 * DIMN, nullptr);
    }
  }

  // ---- primal AGG layers (x_p f32 in pouts slots / out0) ----
  const float* xpc = primal;
  for (int i = 0; i < 3; ++i) {
    gemm(ApP, cf, kNV, nullptr, 0, 0, kNV, XT, 0, kNV, kNV, kNV, 16);      // Ap@X
    fin(kNV, 16, 1.f, nullptr, nullptr, 0, nullptr, nullptr, t1);          // t1 bf16
    gemm(t1, 0, 256, nullptr, 0, 0, 256, (const u16*)pWP + i * W3, cf, 256,
         kNV, 256, 4);
    fin(kNV, 4, 1.f, pb + i * 256, nullptr, 0, nullptr, nullptr, fc);      // fc bf16
    tranp(fc, 0, DIMN, TB, kNV, kNV, DIMN);                                // fc^T
    gemm(ApP, cf, kNV, nullptr, 0, 0, kNV, TB, 0, kNV, kNV, kNV, 16);      // Ap@fc
    fin(kNV, 16, 1.f, nullptr, nullptr, 0, nullptr, nullptr, t1);
    gemm(t1, 0, 256, nullptr, 0, 0, 256, (const u16*)pgWP + i * W3, cf, 256,
         kNV, 256, 4);
    float* nxt = (i < 2) ? (pouts + (size_t)(i + 1) * NVD) : out0;
    fin(kNV, 4, 1.f, pgb + i * 256, fc, 1, xpc, nxt, nullptr);             // relu(fc+og)+x
    xpc = nxt;
    if (i < 2) tranp(xpc, 1, DIMN, XT, kNV, kNV, DIMN);
  }

  // ---- dual AGG layers (x_d f32 in douts slots / out1) ----
  const float* xdc = douts;
  tranp(xdc, 1, DIMN, XT, kNF, kNF, DIMN);
  for (int i = 0; i < 3; ++i) {
    gemm(AdP, cf, kNF, nullptr, 0, 0, kNF, XT, 0, kNF, kNF, kNF, 8);
    fin(kNF, 8, 1.f, nullptr, nullptr, 0, nullptr, nullptr, t1);
    gemm(t1, 0, 256, nullptr, 0, 0, 256, (const u16*)dWP + i * W3, cf, 256,
         kNF, 256, 4);
    fin(kNF, 4, 1.f, db + i * 256, nullptr, 0, nullptr, nullptr, fc);
    tranp(fc, 0, DIMN, TB, kNF, kNF, DIMN);
    gemm(AdP, cf, kNF, nullptr, 0, 0, kNF, TB, 0, kNF, kNF, kNF, 8);
    fin(kNF, 8, 1.f, nullptr, nullptr, 0, nullptr, nullptr, t1);
    gemm(t1, 0, 256, nullptr, 0, 0, 256, (const u16*)dgWP + i * W3, cf, 256,
         kNF, 256, 4);
    float* nxt = (i < 2) ? (douts + (size_t)(i + 1) * NFD) : out1;
    fin(kNF, 4, 1.f, dgb + i * 256, fc, 1, xdc, nxt, nullptr);
    xdc = nxt;
    if (i < 2) tranp(xdc, 1, DIMN, XT, kNF, kNF, DIMN);
  }

  // ---- PDF ----
  face_gather_k<<<dim3(kNF), dim3(256), 0, stream>>>(xpc, xdc, faces, t1);  // f bf16
  tranp(t1, 0, DIMN, TB, kNF, kNF, DIMN);                                   // f^T
  // out_dual = relu([x_d, f] @ Wd^T + bd) + x_d   (in-place on out1)
  gemm(xdc, 1, 256, t1, 0, 256, 256, WdP, cf, 512, kNF, 512, 8);
  fin(kNF, 8, 1.f, bd, nullptr, 1, xdc, out1, nullptr);
  // mapped = A @ f  -> bf16 in fc
  gemm(AP, cf, kNF, nullptr, 0, 0, kNF, TB, 0, kNF, kNV, kNF, 16);
  fin(kNV, 16, 1.f, nullptr, nullptr, 0, nullptr, nullptr, fc);
  // out_primal = relu([x_p, mapped] @ Wp^T + bp) + x_p   (in-place on out0)
  gemm(xpc, 1, 256, fc, 0, 256, 256, WpP, cf, 512, kNV, 512, 8);
  fin(kNV, 8, 1.f, bp, nullptr, 1, xpc, out0, nullptr);
}

// Round 6
// 2128.264 us; speedup vs baseline: 1.2146x; 1.0159x over previous
//
#include <hip/hip_runtime.h>

// TwoStreamNet on MI355X — f32 I/O, bf16 MFMA internals.
// R6: fused-epilogue weight GEMMs (S=1, no partials), bf16 split-K partials for
//     adjacency GEMMs, drop single-use conversions (A, weights stay f32).

typedef short short8 __attribute__((ext_vector_type(8)));
typedef float floatx4 __attribute__((ext_vector_type(4)));
typedef unsigned short ushort4v __attribute__((ext_vector_type(4)));
typedef unsigned short u16;

#define DIMN 256
#define GBM 128
#define GBN 256
#define GBK 64

static const int kNV = 6144;
static const int kNF = 12288;
static const int SLAB = 768;

__device__ __forceinline__ float bf2f(u16 u) {
  union { unsigned int i; float f; } x; x.i = ((unsigned int)u) << 16; return x.f;
}
__device__ __forceinline__ u16 f2bf(float f) {
  union { float f; unsigned int i; } x; x.f = f;
  unsigned int r = x.i + 0x7fffu + ((x.i >> 16) & 1u);
  return (u16)(r >> 16);
}
__device__ __forceinline__ void gld_lds16(const void* g, void* l) {
  __builtin_amdgcn_global_load_lds((__attribute__((address_space(1))) void*)(g),
                                   (__attribute__((address_space(3))) void*)(l),
                                   16, 0, 0);
}

// ---------------- GEMM: C = Aop(M x K) * Bt(256 x K)^T ------------------------------
// 512 threads = 8 waves, wave grid 2(M)x4(N), per-wave 64x64 out (4x4 16x16 frags).
// Aop row-major [M][K] split at K1 between A0/A1 (concat inputs). Per-operand is32:
// f32 operands loaded+converted in registers; bf16 operands via global_load_lds.
// fused=0: write split-K partials to P (f32 or bf16 per pbf16), z-slab blockIdx.z.
// fused=1: single-K-pass epilogue t=acc+bias+add(bf16); [relu]; +resid -> outf/out16.
__global__ __launch_bounds__(512, 1)
void gemm_bf16_k(const void* __restrict__ A0, int A0is32,
                 const void* __restrict__ A1, int A1is32, int K1,
                 int lda0, int lda1,
                 const void* __restrict__ Bt, int Btis32, int ldb,
                 void* __restrict__ P, int M, int kchunk, int pbf16,
                 int fused, const float* __restrict__ bias,
                 const u16* __restrict__ addmat, int do_relu,
                 const float* __restrict__ resid,
                 float* __restrict__ outf, u16* __restrict__ out16)
{
  __shared__ __align__(16) u16 As[2][GBM * GBK];   // 2 x 16 KB
  __shared__ __align__(16) u16 Bs[2][GBN * GBK];   // 2 x 32 KB

  const int m0 = blockIdx.x * GBM;
  const int kb = blockIdx.z * kchunk;
  const int nkt = kchunk / GBK;

  const int tid = threadIdx.x;
  const int wid = tid >> 6;        // 0..7
  const int lane = tid & 63;
  const int wr = wid >> 2;         // 0..1 (64-row band)
  const int wc = wid & 3;          // 0..3 (64-col band)
  const int srow = lane >> 3;      // 0..7 rows within 1KB chunk
  const int skk = (lane & 7) << 3; // 0,8,...,56 k-offset

  floatx4 acc[4][4];
  floatx4 zz = {0.f, 0.f, 0.f, 0.f};
#pragma unroll
  for (int i = 0; i < 4; ++i)
#pragma unroll
    for (int j = 0; j < 4; ++j) acc[i][j] = zz;

  auto stage = [&](int buf, int k0) {
    const void* base; int lda, is32, kl;
    if (k0 < K1) { base = A0; lda = lda0; is32 = A0is32; kl = k0; }
    else         { base = A1; lda = lda1; is32 = A1is32; kl = k0 - K1; }
    if (is32) {
      const float* F = (const float*)base;
#pragma unroll
      for (int j = 0; j < 2; ++j) {        // A tile: 16 chunks, 2 per wave
        int c = (wid << 1) + j;
        const float* src = F + (size_t)(m0 + (c << 3) + srow) * lda + kl + skk;
        floatx4 f0 = *(const floatx4*)src;
        floatx4 f1 = *(const floatx4*)(src + 4);
        short8 v;
#pragma unroll
        for (int e = 0; e < 4; ++e) { v[e] = (short)f2bf(f0[e]); v[4 + e] = (short)f2bf(f1[e]); }
        *(short8*)&As[buf][(c << 9) + (lane << 3)] = v;
      }
    } else {
      const u16* U = (const u16*)base;
#pragma unroll
      for (int j = 0; j < 2; ++j) {
        int c = (wid << 1) + j;
        gld_lds16(U + (size_t)(m0 + (c << 3) + srow) * lda + kl + skk,
                  (void*)&As[buf][c << 9]);
      }
    }
    if (Btis32) {
      const float* F = (const float*)Bt;
#pragma unroll
      for (int j = 0; j < 4; ++j) {        // B tile: 32 chunks, 4 per wave
        int c = (wid << 2) + j;
        const float* src = F + (size_t)((c << 3) + srow) * ldb + k0 + skk;
        floatx4 f0 = *(const floatx4*)src;
        floatx4 f1 = *(const floatx4*)(src + 4);
        short8 v;
#pragma unroll
        for (int e = 0; e < 4; ++e) { v[e] = (short)f2bf(f0[e]); v[4 + e] = (short)f2bf(f1[e]); }
        *(short8*)&Bs[buf][(c << 9) + (lane << 3)] = v;
      }
    } else {
      const u16* U = (const u16*)Bt;
#pragma unroll
      for (int j = 0; j < 4; ++j) {
        int c = (wid << 2) + j;
        gld_lds16(U + (size_t)((c << 3) + srow) * ldb + k0 + skk,
                  (void*)&Bs[buf][c << 9]);
      }
    }
  };

  int cur = 0;
  stage(0, kb);
  for (int kt = 0; kt < nkt; ++kt) {
    __syncthreads();  // drains vmcnt+lgkmcnt: staging of `cur` complete
    if (kt + 1 < nkt) stage(cur ^ 1, kb + (kt + 1) * GBK);
#pragma unroll
    for (int ks = 0; ks < 2; ++ks) {
      short8 a[4], b[4];
      const int ko = (ks << 5) + ((lane >> 4) << 3);
#pragma unroll
      for (int mi = 0; mi < 4; ++mi)
        a[mi] = *(const short8*)&As[cur][((wr << 6) + (mi << 4) + (lane & 15)) * GBK + ko];
#pragma unroll
      for (int ni = 0; ni < 4; ++ni)
        b[ni] = *(const short8*)&Bs[cur][((wc << 6) + (ni << 4) + (lane & 15)) * GBK + ko];
#pragma unroll
      for (int mi = 0; mi < 4; ++mi)
#pragma unroll
        for (int ni = 0; ni < 4; ++ni)
          acc[mi][ni] = __builtin_amdgcn_mfma_f32_16x16x32_bf16(a[mi], b[ni], acc[mi][ni], 0, 0, 0);
    }
    cur ^= 1;
  }

  if (fused) {
#pragma unroll
    for (int mi = 0; mi < 4; ++mi) {
#pragma unroll
      for (int ni = 0; ni < 4; ++ni) {
        const int mb = m0 + (wr << 6) + (mi << 4) + ((lane >> 4) << 2);
        const int n = (wc << 6) + (ni << 4) + (lane & 15);
        const float bv = bias ? bias[n] : 0.f;
#pragma unroll
        for (int r = 0; r < 4; ++r) {
          const size_t idx = (size_t)(mb + r) * DIMN + n;
          float t = acc[mi][ni][r] + bv;
          if (addmat) t += bf2f(addmat[idx]);
          if (do_relu) t = fmaxf(t, 0.f);
          if (resid) t += resid[idx];
          if (outf) outf[idx] = t;
          if (out16) out16[idx] = f2bf(t);
        }
      }
    }
  } else if (pbf16) {
    u16* Pz = (u16*)P + (size_t)blockIdx.z * (size_t)M * DIMN;
#pragma unroll
    for (int mi = 0; mi < 4; ++mi) {
#pragma unroll
      for (int ni = 0; ni < 4; ++ni) {
        const int mb = m0 + (wr << 6) + (mi << 4) + ((lane >> 4) << 2);
        const int n = (wc << 6) + (ni << 4) + (lane & 15);
#pragma unroll
        for (int r = 0; r < 4; ++r)
          Pz[(size_t)(mb + r) * DIMN + n] = f2bf(acc[mi][ni][r]);
      }
    }
  } else {
    float* Pz = (float*)P + (size_t)blockIdx.z * (size_t)M * DIMN;
#pragma unroll
    for (int mi = 0; mi < 4; ++mi) {
#pragma unroll
      for (int ni = 0; ni < 4; ++ni) {
        const int mb = m0 + (wr << 6) + (mi << 4) + ((lane >> 4) << 2);
        const int n = (wc << 6) + (ni << 4) + (lane & 15);
#pragma unroll
        for (int r = 0; r < 4; ++r)
          Pz[(size_t)(mb + r) * DIMN + n] = acc[mi][ni][r];
      }
    }
  }
}

// ---- finalize: t = sum_s P[s]*scale (+bias+add); [relu]; +resid -> outf/out16 -----
__global__ __launch_bounds__(256)
void finalize_k(const void* __restrict__ P, int pbf16, int S, int Mrows, float scale,
                const float* __restrict__ bias, const u16* __restrict__ addmat,
                int do_relu, const float* __restrict__ resid,
                float* __restrict__ out, u16* __restrict__ out16)
{
  const size_t MN = (size_t)Mrows * DIMN;
  const size_t i4 = (((size_t)blockIdx.x * blockDim.x) + threadIdx.x) * 4;
  if (i4 >= MN) return;
  floatx4 v = {0.f, 0.f, 0.f, 0.f};
  if (pbf16) {
    const u16* Pu = (const u16*)P;
    for (int s = 0; s < S; ++s) {
      ushort4v p4 = *(const ushort4v*)(Pu + (size_t)s * MN + i4);
#pragma unroll
      for (int j = 0; j < 4; ++j) v[j] += bf2f(p4[j]);
    }
  } else {
    const float* Pf = (const float*)P;
    for (int s = 0; s < S; ++s) v += *(const floatx4*)(Pf + (size_t)s * MN + i4);
  }
  const int n = (int)(i4 & 255);
  floatx4 bf = {0.f,0.f,0.f,0.f}, af = {0.f,0.f,0.f,0.f}, rf = {0.f,0.f,0.f,0.f};
  if (bias) bf = *(const floatx4*)(bias + n);
  if (addmat) {
#pragma unroll
    for (int j = 0; j < 4; ++j) af[j] = bf2f(addmat[i4 + j]);
  }
  if (resid) rf = *(const floatx4*)(resid + i4);
  floatx4 o;
#pragma unroll
  for (int j = 0; j < 4; ++j) {
    float t = v[j] * scale + bf[j] + af[j];
    if (do_relu) t = fmaxf(t, 0.f);
    o[j] = t + rf[j];
  }
  if (out) *(floatx4*)(out + i4) = o;
  if (out16) {
    unsigned long long q = 0;
#pragma unroll
    for (int j = 0; j < 4; ++j) q |= ((unsigned long long)f2bf(o[j])) << (16 * j);
    *(unsigned long long*)(out16 + i4) = q;
  }
}

// -------- transpose (f32 or bf16 in, bf16 out): out[c][r] = in[r][c], 64x64 tiles --
__global__ __launch_bounds__(256)
void transpose_k(const void* __restrict__ in, int is32, int ldin,
                 u16* __restrict__ out, int ldout)
{
  __shared__ __align__(16) u16 t[64][64];
  const int c0 = blockIdx.x << 6;
  const int r0 = blockIdx.y << 6;
  const int tid = threadIdx.x;
  const int lr = tid >> 3;          // 0..31
  const int lc = (tid & 7) << 3;    // 0,8,...,56
#pragma unroll
  for (int h = 0; h < 2; ++h) {
    const int r = lr + (h << 5);
    short8 v;
    if (is32) {
      const float* F = (const float*)in;
      const float* src = F + (size_t)(r0 + r) * ldin + (c0 + lc);
      floatx4 f0 = *(const floatx4*)src;
      floatx4 f1 = *(const floatx4*)(src + 4);
#pragma unroll
      for (int e = 0; e < 4; ++e) { v[e] = (short)f2bf(f0[e]); v[4 + e] = (short)f2bf(f1[e]); }
    } else {
      v = *(const short8*)((const u16*)in + (size_t)(r0 + r) * ldin + (c0 + lc));
    }
    *(short8*)&t[r][lc ^ ((r >> 3) << 3)] = v;
  }
  __syncthreads();
#pragma unroll
  for (int h = 0; h < 2; ++h) {
    const int oc = lr + (h << 5);
    short8 v;
#pragma unroll
    for (int e = 0; e < 8; ++e)
      v[e] = (short)t[lc + e][oc ^ ((lc >> 3) << 3)];
    *(short8*)&out[(size_t)(c0 + oc) * ldout + (r0 + lc)] = v;
  }
}

// -------- elementwise f32 -> bf16 convert (8 elems/thread) --------------------------
__global__ __launch_bounds__(256)
void cvt8_k(const float* __restrict__ in, u16* __restrict__ out, size_t n)
{
  const size_t i = (((size_t)blockIdx.x << 8) + threadIdx.x) << 3;
  if (i >= n) return;
  floatx4 f0 = *(const floatx4*)(in + i);
  floatx4 f1 = *(const floatx4*)(in + i + 4);
  short8 v;
#pragma unroll
  for (int e = 0; e < 4; ++e) { v[e] = (short)f2bf(f0[e]); v[4 + e] = (short)f2bf(f1[e]); }
  *(short8*)(out + i) = v;
}

// -------- f = mean_t |x_p[faces[f,t]] - x_d[f]|  (f32 in, bf16 out) ----------------
__global__ __launch_bounds__(256)
void face_gather_k(const float* __restrict__ xp, const float* __restrict__ xd,
                   const int* __restrict__ faces, u16* __restrict__ f)
{
  const int fi = blockIdx.x;
  const int j = threadIdx.x;
  const int a = faces[fi * 3 + 0];
  const int b = faces[fi * 3 + 1];
  const int c = faces[fi * 3 + 2];
  const float xv = xd[(size_t)fi * DIMN + j];
  const float s = fabsf(xp[(size_t)a * DIMN + j] - xv)
                + fabsf(xp[(size_t)b * DIMN + j] - xv)
                + fabsf(xp[(size_t)c * DIMN + j] - xv);
  f[(size_t)fi * DIMN + j] = f2bf(s * (1.0f / 3.0f));
}

extern "C" void kernel_launch(void* const* d_in, const int* in_sizes, int n_in,
                              void* d_out, int out_size, void* d_ws, size_t ws_size,
                              hipStream_t stream)
{
  (void)in_sizes; (void)n_in; (void)out_size;
  const float* primal   = (const float*)d_in[0];
  const float* A_primal = (const float*)d_in[1];
  const float* A_dual   = (const float*)d_in[2];
  const float* A        = (const float*)d_in[3];
  const int* faces      = (const int*)d_in[4];
  const float* pW  = (const float*)d_in[5];
  const float* pb  = (const float*)d_in[6];
  const float* pgW = (const float*)d_in[7];
  const float* pgb = (const float*)d_in[8];
  const float* dW  = (const float*)d_in[9];
  const float* db  = (const float*)d_in[10];
  const float* dgW = (const float*)d_in[11];
  const float* dgb = (const float*)d_in[12];
  const float* Wp  = (const float*)d_in[13];
  const float* bp  = (const float*)d_in[14];
  const float* Wd  = (const float*)d_in[15];
  const float* bd  = (const float*)d_in[16];

  char* wsp = (char*)d_ws;
  auto alloc = [&](size_t bytes) -> void* {
    void* p = (void*)wsp;
    wsp += (bytes + 255) & ~(size_t)255;
    return p;
  };
  const size_t NVD = (size_t)kNV * DIMN, NFD = (size_t)kNF * DIMN;
  // small buffers (~130 MB)
  u16* XT    = (u16*)alloc(NFD * 2);                 // x^T [256][M] bf16
  u16* TB    = (u16*)alloc((size_t)SLAB * kNV * 2);  // fc^T / f^T / A^T slab (bf16)
  u16* t1    = (u16*)alloc(NFD * 2);                 // Adj@X / Adj@fc / f (bf16)
  u16* fc    = (u16*)alloc(NFD * 2);                 // out_fc / mapped (bf16)
  void* P    = alloc((size_t)8 * NFD * 4);           // split-K partials (<=100.7MB)
  // big bf16 operand cache (~528 MB) — used only if ws_size allows
  const size_t bigElems = (size_t)kNF * kNF + (size_t)kNF * kNV + (size_t)kNV * kNV;
  const size_t need = (size_t)(wsp - (char*)d_ws) + bigElems * 2 + 4096;
  const bool big = ws_size >= need;
  u16 *Ad16 = nullptr, *At16 = nullptr, *Ap16 = nullptr;
  if (big) {
    Ad16 = (u16*)alloc((size_t)kNF * kNF * 2);
    At16 = (u16*)alloc((size_t)kNF * kNV * 2);
    Ap16 = (u16*)alloc((size_t)kNV * kNV * 2);
  }

  float* out0  = (float*)d_out;      // out_primal + x_p
  float* out1  = out0 + NVD;         // out_dual + x_d
  float* pouts = out1 + NFD;         // primal_outs x3 (f32)
  float* douts = pouts + 3 * NVD;    // dual_outs x3 (f32)

  // split-K GEMM -> bf16 partials in P
  auto gemmP = [&](const void* A0p, int a0is32, int lda0,
                   const void* Btp, int ldb, int M, int K, int S) {
    gemm_bf16_k<<<dim3(M / GBM, 1, S), dim3(512), 0, stream>>>(
        A0p, a0is32, nullptr, 0, K, lda0, 0, Btp, 0, ldb, P, M, K / S, 1,
        0, nullptr, nullptr, 0, nullptr, nullptr, nullptr);
  };
  // fused single-pass GEMM with epilogue
  auto gemmF = [&](const void* A0p, int a0is32, int lda0,
                   const void* A1p, int a1is32, int lda1, int K1,
                   const float* Btp, int ldb, int M, int K,
                   const float* bias, const u16* add, int relu,
                   const float* resid, float* outf, u16* out16) {
    gemm_bf16_k<<<dim3(M / GBM, 1, 1), dim3(512), 0, stream>>>(
        A0p, a0is32, A1p, a1is32, K1, lda0, lda1, Btp, 1, ldb, P, M, K, 0,
        1, bias, add, relu, resid, outf, out16);
  };
  auto fin = [&](int M, int S, float scale, float* out, u16* out16) {
    finalize_k<<<dim3((unsigned)((size_t)M * DIMN / 1024)), dim3(256), 0, stream>>>(
        P, 1, S, M, scale, nullptr, nullptr, 0, nullptr, out, out16);
  };
  auto tranp = [&](const void* in, int is32, int ldin, u16* out, int ldout,
                   int R, int C) {
    transpose_k<<<dim3(C / 64, R / 64), dim3(256), 0, stream>>>(
        in, is32, ldin, out, ldout);
  };
  auto cvt = [&](const float* in, u16* out, size_t n) {
    cvt8_k<<<dim3((unsigned)(n / 2048)), dim3(256), 0, stream>>>(in, out, n);
  };

  // ---- one-time operand prep ----
  const void *AdP, *ApP;
  int cf;  // is32 flag for adjacency operands
  if (big) {
    cvt(A_dual, Ad16, (size_t)kNF * kNF);
    cvt(A_primal, Ap16, (size_t)kNV * kNV);
    tranp(A, 1, kNF, At16, kNV, kNV, kNF);             // At16 [12288][6144] bf16
    AdP = Ad16; ApP = Ap16; cf = 0;
  } else {
    AdP = A_dual; ApP = A_primal; cf = 1;
  }

  // ---- prep: XT = primal^T [256][NV] (bf16); pouts[0] = primal (f32 copy) ----
  tranp(primal, 1, DIMN, XT, kNV, kNV, DIMN);
  hipMemcpyAsync(pouts, primal, NVD * 4, hipMemcpyDeviceToDevice, stream);

  // ---- x_d = (1/3) A^T @ primal ----
  if (big) {
    gemmP(At16, 0, kNV, XT, kNV, kNF, kNV, 8);
    fin(kNF, 8, 1.0f / 3.0f, douts, nullptr);
  } else {
    for (int s = 0; s < kNF / SLAB; ++s) {
      const int m0 = s * SLAB;
      tranp(A + m0, 1, kNF, TB, kNV, kNV, SLAB);       // A^T slab [768][6144]
      gemmP(TB, 0, kNV, XT, kNV, SLAB, kNV, 16);
      fin(SLAB, 16, 1.0f / 3.0f, douts + (size_t)m0 * DIMN, nullptr);
    }
  }

  // ---- primal AGG layers (x_p f32 in pouts slots / out0) ----
  const float* xpc = primal;
  for (int i = 0; i < 3; ++i) {
    gemmP(ApP, cf, kNV, XT, kNV, kNV, kNV, 16);                 // Ap@X -> P
    fin(kNV, 16, 1.f, nullptr, t1);                             // t1 bf16
    gemmF(t1, 0, 256, nullptr, 0, 0, 256, pW + (size_t)i * 65536, 256,
          kNV, 256, pb + i * 256, nullptr, 0, nullptr, nullptr, fc);   // fc bf16
    tranp(fc, 0, DIMN, TB, kNV, kNV, DIMN);                     // fc^T
    gemmP(ApP, cf, kNV, TB, kNV, kNV, kNV, 16);                 // Ap@fc -> P
    fin(kNV, 16, 1.f, nullptr, t1);
    float* nxt = (i < 2) ? (pouts + (size_t)(i + 1) * NVD) : out0;
    gemmF(t1, 0, 256, nullptr, 0, 0, 256, pgW + (size_t)i * 65536, 256,
          kNV, 256, pgb + i * 256, fc, 1, xpc, nxt, nullptr);   // relu(fc+og)+x
    xpc = nxt;
    if (i < 2) tranp(xpc, 1, DIMN, XT, kNV, kNV, DIMN);
  }

  // ---- dual AGG layers (x_d f32 in douts slots / out1) ----
  const float* xdc = douts;
  tranp(xdc, 1, DIMN, XT, kNF, kNF, DIMN);
  for (int i = 0; i < 3; ++i) {
    gemmP(AdP, cf, kNF, XT, kNF, kNF, kNF, 8);
    fin(kNF, 8, 1.f, nullptr, t1);
    gemmF(t1, 0, 256, nullptr, 0, 0, 256, dW + (size_t)i * 65536, 256,
          kNF, 256, db + i * 256, nullptr, 0, nullptr, nullptr, fc);
    tranp(fc, 0, DIMN, TB, kNF, kNF, DIMN);
    gemmP(AdP, cf, kNF, TB, kNF, kNF, kNF, 8);
    fin(kNF, 8, 1.f, nullptr, t1);
    float* nxt = (i < 2) ? (douts + (size_t)(i + 1) * NFD) : out1;
    gemmF(t1, 0, 256, nullptr, 0, 0, 256, dgW + (size_t)i * 65536, 256,
          kNF, 256, dgb + i * 256, fc, 1, xdc, nxt, nullptr);
    xdc = nxt;
    if (i < 2) tranp(xdc, 1, DIMN, XT, kNF, kNF, DIMN);
  }

  // ---- PDF ----
  face_gather_k<<<dim3(kNF), dim3(256), 0, stream>>>(xpc, xdc, faces, t1);  // f bf16
  tranp(t1, 0, DIMN, TB, kNF, kNF, DIMN);                                   // f^T
  // out_dual = relu([x_d, f] @ Wd^T + bd) + x_d   (in-place on out1)
  gemmF(xdc, 1, 256, t1, 0, 256, 256, Wd, 512, kNF, 512,
        bd, nullptr, 1, xdc, out1, nullptr);
  // mapped = A @ f  -> bf16 in fc   (A stays f32: single use)
  gemmP(A, 1, kNF, TB, kNF, kNV, kNF, 16);
  fin(kNV, 16, 1.f, nullptr, fc);
  // out_primal = relu([x_p, mapped] @ Wp^T + bp) + x_p   (in-place on out0)
  gemmF(xpc, 1, 256, fc, 0, 256, 256, Wp, 512, kNV, 512,
        bp, nullptr, 1, xpc, out0, nullptr);
}